// Round 9
// baseline (404.910 us; speedup 1.0000x reference)
//
#include <hip/hip_runtime.h>
#include <hip/hip_bf16.h>
#include <stdint.h>

#define NUM_EMB 4096
#define EMB_DIM 256
#define NVEC 65536                     // 64*32*32
#define OUT0_SIZE (NVEC * EMB_DIM)     // z_q_ste elements; loss scalar follows
#define MTILE 128                      // z rows per block
#define NTILE 64                       // codebook entries per iteration
#define DCONST 0.0625f                 // positivity shift for packed distance

typedef __bf16 bf16x8 __attribute__((ext_vector_type(8)));
typedef float floatx16 __attribute__((ext_vector_type(16)));

static __device__ __forceinline__ unsigned int f2bf(float f) {
  unsigned int u = __float_as_uint(f);
  return (u + 0x7fffu + ((u >> 16) & 1u)) >> 16;  // RNE fp32->bf16
}

// Prep: codebook fp32 -> bf16 in K-MAJOR FRAGMENT layout (ws), ||e||^2+DCONST
// (ws), zero loss slot. Packed layout: 16B chunk for (entry e, k=ks*16+h*8..)
// lives at chunk index (e>>5)*1024 + ks*64 + h*32 + (e&31). A wave's
// B-fragment load (64 lanes = h*32+eL) is then 64 CONSECUTIVE chunks = 1KB
// fully-coalesced, and consecutive ks are sequential -> pure streaming.
__global__ void __launch_bounds__(256) vq_prep(const float* __restrict__ cbf,
                                               unsigned short* __restrict__ cbb,
                                               float* __restrict__ enorm,
                                               float* __restrict__ out) {
  int w = threadIdx.x >> 6;
  int lane = threadIdx.x & 63;
  int row = blockIdx.x * 4 + w;
  float4 v = ((const float4*)(cbf + (size_t)row * EMB_DIM))[lane];
  float ss = v.x * v.x + v.y * v.y + v.z * v.z + v.w * v.w;
  ushort4 b;
  b.x = (unsigned short)f2bf(v.x);
  b.y = (unsigned short)f2bf(v.y);
  b.z = (unsigned short)f2bf(v.z);
  b.w = (unsigned short)f2bf(v.w);
  // lane covers k = 4*lane..4*lane+3: ks = lane>>2, h = (lane>>1)&1, q = lane&1
  {
    int cgrp = row >> 5, eL = row & 31;
    int ks = lane >> 2, h = (lane >> 1) & 1, q = lane & 1;
    size_t off16 = (size_t)cgrp * 1024 + ks * 64 + h * 32 + eL;
    *(ushort4*)((unsigned char*)cbb + off16 * 16 + q * 8) = b;
  }
#pragma unroll
  for (int m = 1; m < 64; m <<= 1) ss += __shfl_xor(ss, m, 64);
  if (lane == 0) enorm[row] = ss + DCONST;
  if (blockIdx.x == 0 && threadIdx.x == 0) out[OUT0_SIZE] = 0.0f;
}

// Main: distance-GEMM streaming B from L1/L2 (packed fragment layout, fully
// coalesced 1KB wave-loads) at 4 WAVES/SIMD: 512-thread blocks, 8 waves of
// 32 rows x 32 cols, <=128 VGPR/wave enforced -> 16 waves/CU. Four
// independent vmcnt chains per SIMD + 4-deep per-wave rolling window hide
// L2 latency; NO LDS staging, NO main-loop barriers (waves free-run).
__global__ void __launch_bounds__(512, 4) vq_main(const float* __restrict__ z,
                                                  const float* __restrict__ cbf,
                                                  const unsigned short* __restrict__ cbb,
                                                  const float* __restrict__ enorm,
                                                  float* __restrict__ out) {
  __shared__ unsigned int minlds[2][MTILE];
  __shared__ int idx_lds[MTILE];
  __shared__ float wsum[8];
  __shared__ float zwsum[4];

  const int t = threadIdx.x;
  const int w = t >> 6;        // 8 waves
  const int lane = t & 63;
  const int h = lane >> 5;     // half-wave
  const int eL = lane & 31;
  const int rg = w >> 1;       // row group: rows rg*32..+31 of the block tile
  const int cg = w & 1;        // col group: cols cg*32..+31 of each 64-entry tile
  const int blk = blockIdx.x;
  const int row_base = blk * MTILE + rg * 32;

  // ---- A-phase: 32 z rows x D=256 as bf16 into registers.
  // A layout for 32x32x16: m = lane&31, k = (lane>>5)*8 + j, per 16-k step.
  uint4 afrag[16];
  float zn = 0.f;
  {
    const float* rp = z + (size_t)(row_base + eL) * EMB_DIM + h * 8;
#pragma unroll
    for (int ks = 0; ks < 16; ++ks) {
      float4 a0 = *(const float4*)(rp + ks * 16);
      float4 a1 = *(const float4*)(rp + ks * 16 + 4);
      zn += a0.x * a0.x + a0.y * a0.y + a0.z * a0.z + a0.w * a0.w
          + a1.x * a1.x + a1.y * a1.y + a1.z * a1.z + a1.w * a1.w;
      uint4 r;
      r.x = f2bf(a0.x) | (f2bf(a0.y) << 16);
      r.y = f2bf(a0.z) | (f2bf(a0.w) << 16);
      r.z = f2bf(a1.x) | (f2bf(a1.y) << 16);
      r.w = f2bf(a1.z) | (f2bf(a1.w) << 16);
      afrag[ks] = r;
    }
    zn += __shfl_xor(zn, 32, 64);  // both col-halves of the lane's row
  }
  // Sum ||z||^2 over this wave's 32 rows (cg==0 waves cover all 128 rows).
  if (cg == 0) {
    float zs = zn;
#pragma unroll
    for (int m = 1; m <= 16; m <<= 1) zs += __shfl_xor(zs, m, 64);
    if (lane == 0) zwsum[rg] = zs;
  }

  // Running packed argmin: top-20 bits of positive distance | 12-bit col.
  unsigned int pmin[16];
#pragma unroll
  for (int s = 0; s < 16; ++s) pmin[s] = 0xFFFFFFFFu;

  // B stream: wave's 32-col slice of tile tt = packed chunk (2*tt+cg),
  // 16KB contiguous; per-lane address = scalar base + lo*16 (uniform strides
  // -> SGPR base + imm offsets). 4-deep rolling window: slot ks&3 holds step
  // ks; after consuming, reload with step ks+4 (next tile for ks>=12).
  const int lo = h * 32 + eL;
  const int col = cg * 32 + eL;
  const uint4* base0 = (const uint4*)cbb + (size_t)cg * 1024 + lo;
  const uint4* base = base0;

  uint4 bw[4];
#pragma unroll
  for (int j = 0; j < 4; ++j) bw[j] = base[j * 64];

  float enC = enorm[col];
  float enN = enC;

  for (int tt = 0; tt < 64; ++tt) {
    const uint4* nb = (tt < 63) ? (base + 2048) : base0;  // wrap: in-bounds, never consumed
    if (tt < 63) enN = enorm[(tt + 1) * 64 + col];

    floatx16 acc;
#pragma unroll
    for (int r = 0; r < 16; ++r) acc[r] = 0.f;

#pragma unroll
    for (int ks = 0; ks < 16; ++ks) {
      bf16x8 b = __builtin_bit_cast(bf16x8, bw[ks & 3]);
      acc = __builtin_amdgcn_mfma_f32_32x32x16_bf16(
          __builtin_bit_cast(bf16x8, afrag[ks]), b, acc, 0, 0, 0);
      // reload same slot with data 4 steps ahead ((ks+4)&3 == ks&3)
      bw[ks & 3] = (ks < 12) ? base[(ks + 4) * 64] : nb[(ks - 12) * 64];
    }

    // d = -2*(z.e) + (||e||^2 + C) > 0; pack top-20 bits with col index
    // ((d & M) | (colb & ~M) fuses to v_bfi_b32).
    unsigned int colb = (unsigned int)(tt * 64 + col);
#pragma unroll
    for (int reg = 0; reg < 16; ++reg) {
      float d = fmaf(-2.f, acc[reg], enC);
      unsigned int p = (__float_as_uint(d) & 0xFFFFF000u) | (colb & 0x00000FFFu);
      pmin[reg] = min(pmin[reg], p);
    }

    base = nb;
    enC = enN;
    // no barrier: waves free-run over the codebook stream
  }

  // Reduce over the 32 col-lanes (xor 1..16 stays within half-wave; halves
  // cover disjoint row sets). Packed u32 min = (distance, index) lexicographic
  // -> smallest-index tiebreak like np.argmin.
#pragma unroll
  for (int s = 0; s < 16; ++s) {
    unsigned int v = pmin[s];
#pragma unroll
    for (int m = 1; m <= 16; m <<= 1) {
      unsigned int o = __shfl_xor(v, m, 64);
      if (o < v) v = o;
    }
    pmin[s] = v;
  }
  // C/D layout 32x32: row = (reg&3) + 8*(reg>>2) + 4*(lane>>5), col = lane&31.
  if (eL == 0) {
#pragma unroll
    for (int s = 0; s < 16; ++s) {
      int rowl = rg * 32 + (s & 3) + 8 * (s >> 2) + 4 * h;
      minlds[cg][rowl] = pmin[s];
    }
  }
  __syncthreads();

  // Combine col-halves; recover idx + distance; loss = sum(||z||^2 + d - C).
  float rl = 0.f;
  if (t < MTILE) {
    unsigned int m0 = minlds[0][t], m1 = minlds[1][t];
    unsigned int m = m1 < m0 ? m1 : m0;
    idx_lds[t] = (int)(m & 0xFFFu);
    rl = __uint_as_float(m & 0xFFFFF000u) - DCONST;
  }
#pragma unroll
  for (int m = 1; m < 64; m <<= 1) rl += __shfl_xor(rl, m, 64);
  if (lane == 0) wsum[w] = rl;
  __syncthreads();
  if (t == 0) {
    float s = ((wsum[0] + wsum[1]) + (wsum[2] + wsum[3]))
            + ((wsum[4] + wsum[5]) + (wsum[6] + wsum[7]))
            + (zwsum[0] + zwsum[1]) + (zwsum[2] + zwsum[3]);
    atomicAdd(out + OUT0_SIZE, s * (1.25f / (float)OUT0_SIZE));
  }

  // Gather phase: out = codebook[idx] (== z + (z_q - z) to ~3e-7).
#pragma unroll 4
  for (int j = 0; j < 16; ++j) {
    int id4 = j * 512 + t;     // float4 index within 128x256 tile
    int r = id4 >> 6, c4 = id4 & 63;
    int k = idx_lds[r];
    float4 ev = ((const float4*)(cbf + (size_t)k * EMB_DIM))[c4];
    ((float4*)(out + (size_t)(blk * MTILE + r) * EMB_DIM))[c4] = ev;
  }
}

extern "C" void kernel_launch(void* const* d_in, const int* in_sizes, int n_in,
                              void* d_out, int out_size, void* d_ws, size_t ws_size,
                              hipStream_t stream) {
  const float* z = (const float*)d_in[0];
  const float* cbf = (const float*)d_in[1];
  unsigned short* cbb = (unsigned short*)d_ws;                           // 2 MB packed bf16 codebook
  float* enorm = (float*)((char*)d_ws + (size_t)NUM_EMB * EMB_DIM * 2);  // +16 KB
  float* out = (float*)d_out;
  vq_prep<<<NUM_EMB / 4, 256, 0, stream>>>(cbf, cbb, enorm, out);
  vq_main<<<NVEC / MTILE, 512, 0, stream>>>(z, cbf, cbb, enorm, out);
}